// Round 6
// baseline (256.953 us; speedup 1.0000x reference)
//
#include <hip/hip_runtime.h>
#include <math.h>

#define N_NODES 10000
#define N_EDGES 320000
#define CAP 128        // max in-degree bucket capacity (mean 32, +17 sigma)
#define TN 32768       // gate table samples over [0, 8); step = 1/4096
#define TSCALE 4096.0f // TN / 8

__device__ __forceinline__ float silu_f(float x) {
    return x / (1.0f + __expf(-x));
}

// ---------------- kernel 1 (prep): blocks 0..39  -> node Ai MLP + deg clear
//                                   blocks 40..168 -> gates(r) table build
// gates(r) is a scalar function of r (weights fixed per call): tabulate it so
// the 320K-edge kernel does a 2-tap lerp instead of a 4800-FMA MLP (which the
// occupancy-targeting scheduler spilled to scratch at 48 VGPRs: r2/r4 evidence,
// WRITE_SIZE 32MB vs 17MB legitimate, 78us).
__global__ __attribute__((amdgpu_waves_per_eu(1, 4))) __launch_bounds__(256)
void prep_kernel(
    const float* __restrict__ atom_emb, const int* __restrict__ A,
    const float* __restrict__ w1, const float* __restrict__ b1,
    const float* __restrict__ w2, const float* __restrict__ b2,
    const float* __restrict__ fw1, const float* __restrict__ fb1,
    const float* __restrict__ fw2, const float* __restrict__ fb2,
    const float* __restrict__ fw3, const float* __restrict__ fb3,
    float* __restrict__ Ai, float4* __restrict__ tab, int* __restrict__ deg)
{
    if (blockIdx.x < 40) {
        int n = blockIdx.x * 256 + threadIdx.x;
        if (n >= N_NODES) return;
        deg[n] = 0;
        int a = A[n];
        float emb[16];
        #pragma unroll
        for (int i = 0; i < 16; ++i) emb[i] = atom_emb[a * 16 + i];
        float acc[8];
        #pragma unroll
        for (int o = 0; o < 8; ++o) acc[o] = b2[o];
        #pragma unroll 4
        for (int j = 0; j < 64; ++j) {
            float s0 = b1[j], s1 = 0.f;
            #pragma unroll
            for (int i = 0; i < 16; i += 2) {
                s0 += emb[i]     * w1[i * 64 + j];
                s1 += emb[i + 1] * w1[(i + 1) * 64 + j];
            }
            float h = silu_f(s0 + s1);
            #pragma unroll
            for (int o = 0; o < 8; ++o) acc[o] += h * w2[j * 8 + o];
        }
        #pragma unroll
        for (int o = 0; o < 8; ++o) Ai[n * 8 + o] = acc[o];
        return;
    }

    // ---- table build: t in [0, TN] inclusive (TN+1 entries) ----
    int t = (blockIdx.x - 40) * 256 + threadIdx.x;
    if (t > TN) return;
    float r = (float)t * (1.0f / TSCALE);

    // radial basis: d_i = r*2.2 - (i+1); rb = exp(-d^2)/1.12*sqrt(10)
    float rb[10];
    float x = r * 2.2f;
    #pragma unroll
    for (int i = 0; i < 10; ++i) {
        float d = x - (float)(i + 1);
        rb[i] = __expf(-d * d) * 2.8234622f;
    }
    // fc1 (weights wave-uniform: all lanes same j,i -> scalar loads)
    float g1[64];
    #pragma unroll 4
    for (int j = 0; j < 64; ++j) {
        float s = fb1[j];
        #pragma unroll
        for (int i = 0; i < 10; ++i) s += rb[i] * fw1[i * 64 + j];
        g1[j] = silu_f(s);
    }
    // fc2 + fc3 (only gate columns 0,3,9 survive the l2==0 path filter)
    float gate0 = fb3[0], gate3 = fb3[3], gate9 = fb3[9];
    for (int j = 0; j < 64; ++j) {
        float a0 = fb2[j], a1 = 0.f, a2 = 0.f, a3 = 0.f;
        #pragma unroll
        for (int i = 0; i < 64; i += 4) {
            a0 += g1[i]     * fw2[i * 64 + j];
            a1 += g1[i + 1] * fw2[(i + 1) * 64 + j];
            a2 += g1[i + 2] * fw2[(i + 2) * 64 + j];
            a3 += g1[i + 3] * fw2[(i + 3) * 64 + j];
        }
        float h = silu_f((a0 + a1) + (a2 + a3));
        gate0 += h * fw3[j * 15 + 0];
        gate3 += h * fw3[j * 15 + 3];
        gate9 += h * fw3[j * 15 + 9];
    }
    tab[t] = make_float4(gate0, gate3, gate9, 0.f);
}

// ---------------- kernel 2: per-edge geometry + table lookup -> q[e] + bucket --
// q[e] = (gate0, gate3*Y1[3], gate9*Y2[5]): 9 floats in a 12-float slot.
__global__ __launch_bounds__(256) void edge_kernel(
    const float* __restrict__ pos, const float* __restrict__ edge_shifts,
    const float* __restrict__ cell, const int* __restrict__ batch,
    const int* __restrict__ edge_src, const int* __restrict__ edge_dst,
    const float4* __restrict__ tab,
    float* __restrict__ Q, int* __restrict__ deg, int* __restrict__ elist)
{
    int e = blockIdx.x * blockDim.x + threadIdx.x;
    if (e >= N_EDGES) return;

    int src = edge_src[e], dst = edge_dst[e];
    int b = batch[src];

    float s0 = edge_shifts[e * 3 + 0];
    float s1 = edge_shifts[e * 3 + 1];
    float s2 = edge_shifts[e * 3 + 2];
    const float* Cb = cell + b * 9;
    float shx = s0 * Cb[0] + s1 * Cb[3] + s2 * Cb[6];
    float shy = s0 * Cb[1] + s1 * Cb[4] + s2 * Cb[7];
    float shz = s0 * Cb[2] + s1 * Cb[5] + s2 * Cb[8];

    float vx = pos[dst * 3 + 0] - pos[src * 3 + 0] + shx;
    float vy = pos[dst * 3 + 1] - pos[src * 3 + 1] + shy;
    float vz = pos[dst * 3 + 2] - pos[src * 3 + 2] + shz;

    float r = sqrtf(vx * vx + vy * vy + vz * vz);
    float rinv = 1.0f / fmaxf(r, 1e-8f);
    float nx = vx * rinv, ny = vy * rinv, nz = vz * rinv;

    // gate table lookup, linear interp
    float tf = fminf(r * TSCALE, (float)(TN - 1));
    int   i0 = (int)tf;
    float fr = tf - (float)i0;
    float4 ga = tab[i0];
    float4 gb = tab[i0 + 1];
    float gate0 = ga.x + fr * (gb.x - ga.x);
    float gate3 = ga.y + fr * (gb.y - ga.y);
    float gate9 = ga.z + fr * (gb.z - ga.z);

    // spherical harmonics (l=1,2)
    const float SQ3 = 1.7320508075688772f;
    const float SQ15 = 3.872983346207417f;
    const float SQ5H = 1.1180339887498949f;   // sqrt(5)/2
    float y1x = SQ3 * nx, y1y = SQ3 * ny, y1z = SQ3 * nz;
    float y20 = SQ15 * nx * ny;
    float y21 = SQ15 * ny * nz;
    float y22 = SQ5H * (3.0f * nz * nz - 1.0f);
    float y23 = SQ15 * nx * nz;
    float y24 = 0.5f * SQ15 * (nx * nx - ny * ny);

    float* Qe = Q + (size_t)e * 12;
    *(float4*)(Qe + 0) = make_float4(gate0, gate3 * y1x, gate3 * y1y, gate3 * y1z);
    *(float4*)(Qe + 4) = make_float4(gate9 * y20, gate9 * y21, gate9 * y22, gate9 * y23);
    Qe[8] = gate9 * y24;

    int pos_ = atomicAdd(&deg[dst], 1);
    if (pos_ < CAP) elist[dst * CAP + pos_] = e;
}

// ---------------- kernel 3: fused gather + tp_w contraction + output ------------
// Block = 256 threads = 4 waves = 4 nodes.
// Phase 1: wave wv gathers M[n][u][9] (lane = slot*8+u, shfl reduce over slots).
// Phase 2: 128 threads contract with tp_w and write out[n][288].
__global__ __launch_bounds__(256) void gather_out_kernel(
    const int* __restrict__ deg, const int* __restrict__ elist,
    const int* __restrict__ edge_src, const float* __restrict__ Q,
    const float* __restrict__ Ai, const float* __restrict__ tp_w,
    float* __restrict__ out)
{
    __shared__ float sM[4][72];
    __shared__ float sA[4][8];
    int tid = threadIdx.x;
    int lane = tid & 63;
    int wv = tid >> 6;
    int nodeBase = blockIdx.x * 4;
    int n1 = nodeBase + wv;
    int u1 = lane & 7;
    int slot = lane >> 3;

    int d = deg[n1];
    int dc = d > CAP ? CAP : d;

    float acc[9];
    #pragma unroll
    for (int k = 0; k < 9; ++k) acc[k] = 0.f;

    const int* el = elist + n1 * CAP;
    for (int i = slot; i < dc; i += 8) {
        int e = el[i];
        int src = edge_src[e];
        float au = Ai[src * 8 + u1];
        const float* q = Q + (size_t)e * 12;
        float4 qa = *(const float4*)(q + 0);
        float4 qb = *(const float4*)(q + 4);
        float  qc = q[8];
        acc[0] += qa.x * au; acc[1] += qa.y * au; acc[2] += qa.z * au;
        acc[3] += qa.w * au; acc[4] += qb.x * au; acc[5] += qb.y * au;
        acc[6] += qb.z * au; acc[7] += qb.w * au; acc[8] += qc   * au;
    }

    #pragma unroll
    for (int m = 8; m < 64; m <<= 1) {
        #pragma unroll
        for (int k = 0; k < 9; ++k) acc[k] += __shfl_xor(acc[k], m, 64);
    }

    if (slot == 0) {
        #pragma unroll
        for (int k = 0; k < 9; ++k) sM[wv][u1 * 9 + k] = acc[k];
    }
    if (tid < 32) sA[tid >> 3][tid & 7] = Ai[nodeBase * 8 + tid];
    __syncthreads();

    if (tid >= 128) return;
    int ln = tid >> 5, w = tid & 31;
    int n = nodeBase + ln;

    float a[8];
    #pragma unroll
    for (int v = 0; v < 8; ++v) a[v] = sA[ln][v];
    float inv = 1.0f / fmaxf((float)deg[n], 1.0f);

    const float* W0 = tp_w + 0 * 2048;   // path (0,0,0)
    const float* W3 = tp_w + 3 * 2048;   // path (1,0,1)
    const float* W9 = tp_w + 9 * 2048;   // path (2,0,2)

    // l=0 block (32 floats at offset 0)
    {
        float o0 = 0.f;
        #pragma unroll
        for (int u = 0; u < 8; ++u) {
            float c = 0.f;
            #pragma unroll
            for (int v = 0; v < 8; ++v) c += a[v] * W0[(u * 8 + v) * 32 + w];
            o0 += sM[ln][u * 9] * c;
        }
        out[n * 288 + w] = o0 * inv;
    }
    // l=1 block (96 floats at offset 32), layout [w][k], k<3
    {
        float o1[3] = {0.f, 0.f, 0.f};
        #pragma unroll
        for (int u = 0; u < 8; ++u) {
            float c = 0.f;
            #pragma unroll
            for (int v = 0; v < 8; ++v) c += a[v] * W3[(u * 8 + v) * 32 + w];
            #pragma unroll
            for (int k = 0; k < 3; ++k) o1[k] += sM[ln][u * 9 + 1 + k] * c;
        }
        #pragma unroll
        for (int k = 0; k < 3; ++k) out[n * 288 + 32 + w * 3 + k] = o1[k] * inv;
    }
    // l=2 block (160 floats at offset 128), layout [w][k], k<5
    {
        float o2[5] = {0.f, 0.f, 0.f, 0.f, 0.f};
        #pragma unroll
        for (int u = 0; u < 8; ++u) {
            float c = 0.f;
            #pragma unroll
            for (int v = 0; v < 8; ++v) c += a[v] * W9[(u * 8 + v) * 32 + w];
            #pragma unroll
            for (int k = 0; k < 5; ++k) o2[k] += sM[ln][u * 9 + 4 + k] * c;
        }
        #pragma unroll
        for (int k = 0; k < 5; ++k) out[n * 288 + 128 + w * 5 + k] = o2[k] * inv;
    }
}

// ---------------- launch ---------------------------------------------------------
extern "C" void kernel_launch(void* const* d_in, const int* in_sizes, int n_in,
                              void* d_out, int out_size, void* d_ws, size_t ws_size,
                              hipStream_t stream) {
    const float* pos         = (const float*)d_in[0];
    const float* edge_shifts = (const float*)d_in[1];
    const float* cell        = (const float*)d_in[2];
    const float* atom_emb    = (const float*)d_in[3];
    const float* mlp_w1      = (const float*)d_in[4];
    const float* mlp_b1      = (const float*)d_in[5];
    const float* mlp_w2      = (const float*)d_in[6];
    const float* mlp_b2      = (const float*)d_in[7];
    const float* fc_w1       = (const float*)d_in[8];
    const float* fc_b1       = (const float*)d_in[9];
    const float* fc_w2       = (const float*)d_in[10];
    const float* fc_b2       = (const float*)d_in[11];
    const float* fc_w3       = (const float*)d_in[12];
    const float* fc_b3       = (const float*)d_in[13];
    const float* tp_w        = (const float*)d_in[14];
    const int*   A           = (const int*)d_in[15];
    const int*   batch       = (const int*)d_in[16];
    const int*   edge_src    = (const int*)d_in[17];
    const int*   edge_dst    = (const int*)d_in[18];
    float* out = (float*)d_out;

    // workspace layout (16B aligned):
    // floats: Q[320000*12] | Ai[80000] | tab[(TN+1)*4] ; ints: deg[10000] | elist[10000*128]
    float*  Q   = (float*)d_ws;
    float*  Ai  = Q + (size_t)N_EDGES * 12;
    float4* tab = (float4*)(Ai + N_NODES * 8);
    int*    deg   = (int*)(tab + (TN + 1));
    int*    elist = deg + N_NODES;
    // total: ~22 MB

    // prep: 40 blocks Ai+deg-clear, 129 blocks table (33024 threads >= TN+1)
    prep_kernel<<<169, 256, 0, stream>>>(
        atom_emb, A, mlp_w1, mlp_b1, mlp_w2, mlp_b2,
        fc_w1, fc_b1, fc_w2, fc_b2, fc_w3, fc_b3, Ai, tab, deg);

    edge_kernel<<<N_EDGES / 256, 256, 0, stream>>>(
        pos, edge_shifts, cell, batch, edge_src, edge_dst,
        tab, Q, deg, elist);

    gather_out_kernel<<<N_NODES / 4, 256, 0, stream>>>(
        deg, elist, edge_src, Q, Ai, tp_w, out);
}

// Round 7
// 205.712 us; speedup vs baseline: 1.2491x; 1.2491x over previous
//
#include <hip/hip_runtime.h>
#include <math.h>

#define N_NODES 10000
#define N_EDGES 320000
#define CAP 128        // max in-degree bucket capacity (mean 32, +17 sigma)
#define TN 32768       // gate table samples over [0, 8); step = 1/4096
#define TSCALE 4096.0f // TN / 8
#define BK_BLOCKS 1250 // 1250*256 = 320000 edges
#define AI_BLOCKS 40   // 40*256 >= 10000 nodes
#define TB_BLOCKS 129  // 129*256 >= TN+1 table entries

__device__ __forceinline__ float silu_f(float x) {
    return x / (1.0f + __expf(-x));
}

// ---------------- kernel 1 (fused prep):
//   blocks [0,1250)        : bucket insert (e,src) by dst  -- latency-bound
//   blocks [1250,1290)     : node Ai MLP                   -- small
//   blocks [1290,1419)     : gates(r) table build          -- VALU-bound
// The three roles overlap on the CU array; deg[] is cleared by a prior memset.
__global__ __attribute__((amdgpu_waves_per_eu(1, 2))) __launch_bounds__(256)
void fused_prep_kernel(
    const int* __restrict__ edge_src, const int* __restrict__ edge_dst,
    const float* __restrict__ atom_emb, const int* __restrict__ A,
    const float* __restrict__ w1, const float* __restrict__ b1,
    const float* __restrict__ w2, const float* __restrict__ b2,
    const float* __restrict__ fw1, const float* __restrict__ fb1,
    const float* __restrict__ fw2, const float* __restrict__ fb2,
    const float* __restrict__ fw3, const float* __restrict__ fb3,
    float* __restrict__ Ai, float4* __restrict__ tab,
    int* __restrict__ deg, int2* __restrict__ elist)
{
    int bid = blockIdx.x;
    if (bid < BK_BLOCKS) {
        // ---- bucket insert: the ONLY per-edge scatter work ----
        int e = bid * 256 + threadIdx.x;
        int dst = edge_dst[e];
        int src = edge_src[e];           // coalesced here; saves a scattered load in gather
        int p = atomicAdd(&deg[dst], 1);
        if (p < CAP) elist[dst * CAP + p] = make_int2(e, src);
        return;
    }
    if (bid < BK_BLOCKS + AI_BLOCKS) {
        // ---- node Ai = mlp(atom_emb[A]) ----
        int n = (bid - BK_BLOCKS) * 256 + threadIdx.x;
        if (n >= N_NODES) return;
        int a = A[n];
        float emb[16];
        #pragma unroll
        for (int i = 0; i < 16; ++i) emb[i] = atom_emb[a * 16 + i];
        float acc[8];
        #pragma unroll
        for (int o = 0; o < 8; ++o) acc[o] = b2[o];
        #pragma unroll 4
        for (int j = 0; j < 64; ++j) {
            float s0 = b1[j], s1 = 0.f;
            #pragma unroll
            for (int i = 0; i < 16; i += 2) {
                s0 += emb[i]     * w1[i * 64 + j];
                s1 += emb[i + 1] * w1[(i + 1) * 64 + j];
            }
            float h = silu_f(s0 + s1);
            #pragma unroll
            for (int o = 0; o < 8; ++o) acc[o] += h * w2[j * 8 + o];
        }
        #pragma unroll
        for (int o = 0; o < 8; ++o) Ai[n * 8 + o] = acc[o];
        return;
    }

    // ---- gates(r) table: t in [0, TN] inclusive ----
    int t = (bid - BK_BLOCKS - AI_BLOCKS) * 256 + threadIdx.x;
    if (t > TN) return;
    float r = (float)t * (1.0f / TSCALE);

    float rb[10];
    float x = r * 2.2f;
    #pragma unroll
    for (int i = 0; i < 10; ++i) {
        float d = x - (float)(i + 1);
        rb[i] = __expf(-d * d) * 2.8234622f;
    }
    float g1[64];
    #pragma unroll 4
    for (int j = 0; j < 64; ++j) {
        float s = fb1[j];
        #pragma unroll
        for (int i = 0; i < 10; ++i) s += rb[i] * fw1[i * 64 + j];
        g1[j] = silu_f(s);
    }
    float gate0 = fb3[0], gate3 = fb3[3], gate9 = fb3[9];
    for (int j = 0; j < 64; ++j) {
        float a0 = fb2[j], a1 = 0.f, a2 = 0.f, a3 = 0.f;
        #pragma unroll
        for (int i = 0; i < 64; i += 4) {
            a0 += g1[i]     * fw2[i * 64 + j];
            a1 += g1[i + 1] * fw2[(i + 1) * 64 + j];
            a2 += g1[i + 2] * fw2[(i + 2) * 64 + j];
            a3 += g1[i + 3] * fw2[(i + 3) * 64 + j];
        }
        float h = silu_f((a0 + a1) + (a2 + a3));
        gate0 += h * fw3[j * 15 + 0];
        gate3 += h * fw3[j * 15 + 3];
        gate9 += h * fw3[j * 15 + 9];
    }
    tab[t] = make_float4(gate0, gate3, gate9, 0.f);
}

// ---------------- kernel 2: fused gather (inline geometry) + contraction --------
// Block = 256 threads = 4 waves = 4 nodes; lane = slot*8 + u.
// Phase 1: each slot-group of 8 lanes processes one edge: recompute edge vector,
//          table-lerp gates, Y harmonics (redundant across the 8 u-lanes but the
//          VALU is otherwise idle: r6 showed VALUBusy=1%), accumulate
//          acc[k] += q[k]*Ai[src][u]; shfl-reduce over slots -> M[u][9] in LDS.
// Phase 2: 128 threads contract with tp_w and write out[n][288].
__global__ __launch_bounds__(256) void gather_out_kernel(
    const int* __restrict__ deg, const int2* __restrict__ elist,
    const float* __restrict__ pos, const float* __restrict__ edge_shifts,
    const float* __restrict__ cell, const int* __restrict__ batch,
    const float4* __restrict__ tab, const float* __restrict__ Ai,
    const float* __restrict__ tp_w, float* __restrict__ out)
{
    __shared__ float sM[4][72];
    __shared__ float sA[4][8];
    int tid = threadIdx.x;
    int lane = tid & 63;
    int wv = tid >> 6;
    int nodeBase = blockIdx.x * 4;
    int n1 = nodeBase + wv;
    int u1 = lane & 7;
    int slot = lane >> 3;

    int d = deg[n1];
    int dc = d > CAP ? CAP : d;

    // dst position is loop-invariant (dst == n1)
    float px = pos[n1 * 3 + 0], py = pos[n1 * 3 + 1], pz = pos[n1 * 3 + 2];

    const float SQ3 = 1.7320508075688772f;
    const float SQ15 = 3.872983346207417f;
    const float SQ5H = 1.1180339887498949f;   // sqrt(5)/2

    float acc[9];
    #pragma unroll
    for (int k = 0; k < 9; ++k) acc[k] = 0.f;

    const int2* el = elist + n1 * CAP;
    for (int i = slot; i < dc; i += 8) {
        int2 es = el[i];
        int e = es.x, src = es.y;

        float s0 = edge_shifts[e * 3 + 0];
        float s1 = edge_shifts[e * 3 + 1];
        float s2 = edge_shifts[e * 3 + 2];
        int b = batch[src];
        const float* Cb = cell + b * 9;
        float vx = px - pos[src * 3 + 0] + s0 * Cb[0] + s1 * Cb[3] + s2 * Cb[6];
        float vy = py - pos[src * 3 + 1] + s0 * Cb[1] + s1 * Cb[4] + s2 * Cb[7];
        float vz = pz - pos[src * 3 + 2] + s0 * Cb[2] + s1 * Cb[5] + s2 * Cb[8];

        float r = sqrtf(vx * vx + vy * vy + vz * vz);
        float rinv = 1.0f / fmaxf(r, 1e-8f);
        float nx = vx * rinv, ny = vy * rinv, nz = vz * rinv;

        float tf = fminf(r * TSCALE, (float)(TN - 1));
        int   i0 = (int)tf;
        float fr = tf - (float)i0;
        float4 ga = tab[i0];
        float4 gb = tab[i0 + 1];
        float gate0 = ga.x + fr * (gb.x - ga.x);
        float gate3 = ga.y + fr * (gb.y - ga.y);
        float gate9 = ga.z + fr * (gb.z - ga.z);

        float au = Ai[src * 8 + u1];

        acc[0] += gate0 * au;
        float g3a = gate3 * au;
        acc[1] += g3a * (SQ3 * nx);
        acc[2] += g3a * (SQ3 * ny);
        acc[3] += g3a * (SQ3 * nz);
        float g9a = gate9 * au;
        acc[4] += g9a * (SQ15 * nx * ny);
        acc[5] += g9a * (SQ15 * ny * nz);
        acc[6] += g9a * (SQ5H * (3.0f * nz * nz - 1.0f));
        acc[7] += g9a * (SQ15 * nx * nz);
        acc[8] += g9a * (0.5f * SQ15 * (nx * nx - ny * ny));
    }

    #pragma unroll
    for (int m = 8; m < 64; m <<= 1) {
        #pragma unroll
        for (int k = 0; k < 9; ++k) acc[k] += __shfl_xor(acc[k], m, 64);
    }

    if (slot == 0) {
        #pragma unroll
        for (int k = 0; k < 9; ++k) sM[wv][u1 * 9 + k] = acc[k];
    }
    if (tid < 32) sA[tid >> 3][tid & 7] = Ai[nodeBase * 8 + tid];
    __syncthreads();

    if (tid >= 128) return;
    int ln = tid >> 5, w = tid & 31;
    int n = nodeBase + ln;

    float a[8];
    #pragma unroll
    for (int v = 0; v < 8; ++v) a[v] = sA[ln][v];
    float inv = 1.0f / fmaxf((float)deg[n], 1.0f);

    const float* W0 = tp_w + 0 * 2048;   // path (0,0,0)
    const float* W3 = tp_w + 3 * 2048;   // path (1,0,1)
    const float* W9 = tp_w + 9 * 2048;   // path (2,0,2)

    // l=0 block (32 floats at offset 0)
    {
        float o0 = 0.f;
        #pragma unroll
        for (int u = 0; u < 8; ++u) {
            float c = 0.f;
            #pragma unroll
            for (int v = 0; v < 8; ++v) c += a[v] * W0[(u * 8 + v) * 32 + w];
            o0 += sM[ln][u * 9] * c;
        }
        out[n * 288 + w] = o0 * inv;
    }
    // l=1 block (96 floats at offset 32), layout [w][k], k<3
    {
        float o1[3] = {0.f, 0.f, 0.f};
        #pragma unroll
        for (int u = 0; u < 8; ++u) {
            float c = 0.f;
            #pragma unroll
            for (int v = 0; v < 8; ++v) c += a[v] * W3[(u * 8 + v) * 32 + w];
            #pragma unroll
            for (int k = 0; k < 3; ++k) o1[k] += sM[ln][u * 9 + 1 + k] * c;
        }
        #pragma unroll
        for (int k = 0; k < 3; ++k) out[n * 288 + 32 + w * 3 + k] = o1[k] * inv;
    }
    // l=2 block (160 floats at offset 128), layout [w][k], k<5
    {
        float o2[5] = {0.f, 0.f, 0.f, 0.f, 0.f};
        #pragma unroll
        for (int u = 0; u < 8; ++u) {
            float c = 0.f;
            #pragma unroll
            for (int v = 0; v < 8; ++v) c += a[v] * W9[(u * 8 + v) * 32 + w];
            #pragma unroll
            for (int k = 0; k < 5; ++k) o2[k] += sM[ln][u * 9 + 4 + k] * c;
        }
        #pragma unroll
        for (int k = 0; k < 5; ++k) out[n * 288 + 128 + w * 5 + k] = o2[k] * inv;
    }
}

// ---------------- launch ---------------------------------------------------------
extern "C" void kernel_launch(void* const* d_in, const int* in_sizes, int n_in,
                              void* d_out, int out_size, void* d_ws, size_t ws_size,
                              hipStream_t stream) {
    const float* pos         = (const float*)d_in[0];
    const float* edge_shifts = (const float*)d_in[1];
    const float* cell        = (const float*)d_in[2];
    const float* atom_emb    = (const float*)d_in[3];
    const float* mlp_w1      = (const float*)d_in[4];
    const float* mlp_b1      = (const float*)d_in[5];
    const float* mlp_w2      = (const float*)d_in[6];
    const float* mlp_b2      = (const float*)d_in[7];
    const float* fc_w1       = (const float*)d_in[8];
    const float* fc_b1       = (const float*)d_in[9];
    const float* fc_w2       = (const float*)d_in[10];
    const float* fc_b2       = (const float*)d_in[11];
    const float* fc_w3       = (const float*)d_in[12];
    const float* fc_b3       = (const float*)d_in[13];
    const float* tp_w        = (const float*)d_in[14];
    const int*   A           = (const int*)d_in[15];
    const int*   batch       = (const int*)d_in[16];
    const int*   edge_src    = (const int*)d_in[17];
    const int*   edge_dst    = (const int*)d_in[18];
    float* out = (float*)d_out;

    // workspace layout (16B aligned):
    // floats: Ai[80000] | tab[(TN+1)*4] ; ints: deg[10000] | elist int2[10000*128]
    float*  Ai  = (float*)d_ws;
    float4* tab = (float4*)(Ai + N_NODES * 8);
    int*    deg   = (int*)(tab + (TN + 1));
    int2*   elist = (int2*)(deg + N_NODES);
    // total: ~11.2 MB

    hipMemsetAsync(deg, 0, N_NODES * sizeof(int), stream);

    fused_prep_kernel<<<BK_BLOCKS + AI_BLOCKS + TB_BLOCKS, 256, 0, stream>>>(
        edge_src, edge_dst, atom_emb, A, mlp_w1, mlp_b1, mlp_w2, mlp_b2,
        fc_w1, fc_b1, fc_w2, fc_b2, fc_w3, fc_b3, Ai, tab, deg, elist);

    gather_out_kernel<<<N_NODES / 4, 256, 0, stream>>>(
        deg, elist, pos, edge_shifts, cell, batch, tab, Ai, tp_w, out);
}

// Round 8
// 200.826 us; speedup vs baseline: 1.2795x; 1.0243x over previous
//
#include <hip/hip_runtime.h>
#include <math.h>

#define N_NODES 10000
#define N_EDGES 320000
#define CAP 128        // max in-degree bucket capacity (mean 32, +17 sigma)
#define TN 32768       // gate table samples over [0, 8); step = 1/4096
#define TSCALE 4096.0f // TN / 8
#define AI_BLOCKS 40   // 40*256 >= 10000 nodes
#define TB_BLOCKS 129  // 129*256 >= TN+1 table entries

__device__ __forceinline__ float silu_f(float x) {
    return x / (1.0f + __expf(-x));
}

// ---------------- kernel 1: bucket insert only ---------------------------------
// Minimal footprint (VGPR ~12, no LDS) so the whole 320K-thread grid is
// co-resident: r7 showed that fusing this with the table build dragged it to
// 2 blocks/CU via a 64KB promote-alloca LDS allocation (g1[64] x 256 thr).
__global__ __launch_bounds__(256) void bucket_kernel(
    const int* __restrict__ edge_src, const int* __restrict__ edge_dst,
    int* __restrict__ deg, int2* __restrict__ elist)
{
    int e = blockIdx.x * 256 + threadIdx.x;
    int dst = edge_dst[e];
    int src = edge_src[e];           // coalesced here; scattered in gather otherwise
    int p = atomicAdd(&deg[dst], 1);
    if (p < CAP) elist[dst * CAP + p] = make_int2(e, src);
}

// ---------------- kernel 2: prep = node Ai MLP + gates(r) table ----------------
// blocks [0,40): Ai; blocks [40,169): table. 169 blocks << chip capacity, so
// per-thread cost is irrelevant; default occupancy heuristics are fine.
__global__ __launch_bounds__(256) void prep_kernel(
    const float* __restrict__ atom_emb, const int* __restrict__ A,
    const float* __restrict__ w1, const float* __restrict__ b1,
    const float* __restrict__ w2, const float* __restrict__ b2,
    const float* __restrict__ fw1, const float* __restrict__ fb1,
    const float* __restrict__ fw2, const float* __restrict__ fb2,
    const float* __restrict__ fw3, const float* __restrict__ fb3,
    float* __restrict__ Ai, float4* __restrict__ tab)
{
    int bid = blockIdx.x;
    if (bid < AI_BLOCKS) {
        int n = bid * 256 + threadIdx.x;
        if (n >= N_NODES) return;
        int a = A[n];
        float emb[16];
        #pragma unroll
        for (int i = 0; i < 16; ++i) emb[i] = atom_emb[a * 16 + i];
        float acc[8];
        #pragma unroll
        for (int o = 0; o < 8; ++o) acc[o] = b2[o];
        #pragma unroll 4
        for (int j = 0; j < 64; ++j) {
            float s0 = b1[j], s1 = 0.f;
            #pragma unroll
            for (int i = 0; i < 16; i += 2) {
                s0 += emb[i]     * w1[i * 64 + j];
                s1 += emb[i + 1] * w1[(i + 1) * 64 + j];
            }
            float h = silu_f(s0 + s1);
            #pragma unroll
            for (int o = 0; o < 8; ++o) acc[o] += h * w2[j * 8 + o];
        }
        #pragma unroll
        for (int o = 0; o < 8; ++o) Ai[n * 8 + o] = acc[o];
        return;
    }

    // ---- gates(r) table: t in [0, TN] inclusive ----
    int t = (bid - AI_BLOCKS) * 256 + threadIdx.x;
    if (t > TN) return;
    float r = (float)t * (1.0f / TSCALE);

    float rb[10];
    float x = r * 2.2f;
    #pragma unroll
    for (int i = 0; i < 10; ++i) {
        float d = x - (float)(i + 1);
        rb[i] = __expf(-d * d) * 2.8234622f;
    }
    float g1[64];
    #pragma unroll 4
    for (int j = 0; j < 64; ++j) {
        float s = fb1[j];
        #pragma unroll
        for (int i = 0; i < 10; ++i) s += rb[i] * fw1[i * 64 + j];
        g1[j] = silu_f(s);
    }
    float gate0 = fb3[0], gate3 = fb3[3], gate9 = fb3[9];
    for (int j = 0; j < 64; ++j) {
        float a0 = fb2[j], a1 = 0.f, a2 = 0.f, a3 = 0.f;
        #pragma unroll
        for (int i = 0; i < 64; i += 4) {
            a0 += g1[i]     * fw2[i * 64 + j];
            a1 += g1[i + 1] * fw2[(i + 1) * 64 + j];
            a2 += g1[i + 2] * fw2[(i + 2) * 64 + j];
            a3 += g1[i + 3] * fw2[(i + 3) * 64 + j];
        }
        float h = silu_f((a0 + a1) + (a2 + a3));
        gate0 += h * fw3[j * 15 + 0];
        gate3 += h * fw3[j * 15 + 3];
        gate9 += h * fw3[j * 15 + 9];
    }
    tab[t] = make_float4(gate0, gate3, gate9, 0.f);
}

// ---------------- kernel 3: fused gather (inline geometry) + contraction --------
// Block = 256 threads = 4 waves = 4 nodes; lane = slot*8 + u.
// Phase 1: each slot-group of 8 lanes processes one edge: recompute edge vector,
//          table-lerp gates, Y harmonics (redundant across the 8 u-lanes but the
//          VALU is otherwise idle: r6 showed VALUBusy=1%), accumulate
//          acc[k] += q[k]*Ai[src][u]; shfl-reduce over slots -> M[u][9] in LDS.
// Phase 2: 128 threads contract with tp_w and write out[n][288].
__global__ __launch_bounds__(256) void gather_out_kernel(
    const int* __restrict__ deg, const int2* __restrict__ elist,
    const float* __restrict__ pos, const float* __restrict__ edge_shifts,
    const float* __restrict__ cell, const int* __restrict__ batch,
    const float4* __restrict__ tab, const float* __restrict__ Ai,
    const float* __restrict__ tp_w, float* __restrict__ out)
{
    __shared__ float sM[4][72];
    __shared__ float sA[4][8];
    int tid = threadIdx.x;
    int lane = tid & 63;
    int wv = tid >> 6;
    int nodeBase = blockIdx.x * 4;
    int n1 = nodeBase + wv;
    int u1 = lane & 7;
    int slot = lane >> 3;

    int d = deg[n1];
    int dc = d > CAP ? CAP : d;

    // dst position is loop-invariant (dst == n1)
    float px = pos[n1 * 3 + 0], py = pos[n1 * 3 + 1], pz = pos[n1 * 3 + 2];

    const float SQ3 = 1.7320508075688772f;
    const float SQ15 = 3.872983346207417f;
    const float SQ5H = 1.1180339887498949f;   // sqrt(5)/2

    float acc[9];
    #pragma unroll
    for (int k = 0; k < 9; ++k) acc[k] = 0.f;

    const int2* el = elist + n1 * CAP;
    for (int i = slot; i < dc; i += 8) {
        int2 es = el[i];
        int e = es.x, src = es.y;

        float s0 = edge_shifts[e * 3 + 0];
        float s1 = edge_shifts[e * 3 + 1];
        float s2 = edge_shifts[e * 3 + 2];
        int b = batch[src];
        const float* Cb = cell + b * 9;
        float vx = px - pos[src * 3 + 0] + s0 * Cb[0] + s1 * Cb[3] + s2 * Cb[6];
        float vy = py - pos[src * 3 + 1] + s0 * Cb[1] + s1 * Cb[4] + s2 * Cb[7];
        float vz = pz - pos[src * 3 + 2] + s0 * Cb[2] + s1 * Cb[5] + s2 * Cb[8];

        float r = sqrtf(vx * vx + vy * vy + vz * vz);
        float rinv = 1.0f / fmaxf(r, 1e-8f);
        float nx = vx * rinv, ny = vy * rinv, nz = vz * rinv;

        float tf = fminf(r * TSCALE, (float)(TN - 1));
        int   i0 = (int)tf;
        float fr = tf - (float)i0;
        float4 ga = tab[i0];
        float4 gb = tab[i0 + 1];
        float gate0 = ga.x + fr * (gb.x - ga.x);
        float gate3 = ga.y + fr * (gb.y - ga.y);
        float gate9 = ga.z + fr * (gb.z - ga.z);

        float au = Ai[src * 8 + u1];

        acc[0] += gate0 * au;
        float g3a = gate3 * au;
        acc[1] += g3a * (SQ3 * nx);
        acc[2] += g3a * (SQ3 * ny);
        acc[3] += g3a * (SQ3 * nz);
        float g9a = gate9 * au;
        acc[4] += g9a * (SQ15 * nx * ny);
        acc[5] += g9a * (SQ15 * ny * nz);
        acc[6] += g9a * (SQ5H * (3.0f * nz * nz - 1.0f));
        acc[7] += g9a * (SQ15 * nx * nz);
        acc[8] += g9a * (0.5f * SQ15 * (nx * nx - ny * ny));
    }

    #pragma unroll
    for (int m = 8; m < 64; m <<= 1) {
        #pragma unroll
        for (int k = 0; k < 9; ++k) acc[k] += __shfl_xor(acc[k], m, 64);
    }

    if (slot == 0) {
        #pragma unroll
        for (int k = 0; k < 9; ++k) sM[wv][u1 * 9 + k] = acc[k];
    }
    if (tid < 32) sA[tid >> 3][tid & 7] = Ai[nodeBase * 8 + tid];
    __syncthreads();

    if (tid >= 128) return;
    int ln = tid >> 5, w = tid & 31;
    int n = nodeBase + ln;

    float a[8];
    #pragma unroll
    for (int v = 0; v < 8; ++v) a[v] = sA[ln][v];
    float inv = 1.0f / fmaxf((float)deg[n], 1.0f);

    const float* W0 = tp_w + 0 * 2048;   // path (0,0,0)
    const float* W3 = tp_w + 3 * 2048;   // path (1,0,1)
    const float* W9 = tp_w + 9 * 2048;   // path (2,0,2)

    // l=0 block (32 floats at offset 0)
    {
        float o0 = 0.f;
        #pragma unroll
        for (int u = 0; u < 8; ++u) {
            float c = 0.f;
            #pragma unroll
            for (int v = 0; v < 8; ++v) c += a[v] * W0[(u * 8 + v) * 32 + w];
            o0 += sM[ln][u * 9] * c;
        }
        out[n * 288 + w] = o0 * inv;
    }
    // l=1 block (96 floats at offset 32), layout [w][k], k<3
    {
        float o1[3] = {0.f, 0.f, 0.f};
        #pragma unroll
        for (int u = 0; u < 8; ++u) {
            float c = 0.f;
            #pragma unroll
            for (int v = 0; v < 8; ++v) c += a[v] * W3[(u * 8 + v) * 32 + w];
            #pragma unroll
            for (int k = 0; k < 3; ++k) o1[k] += sM[ln][u * 9 + 1 + k] * c;
        }
        #pragma unroll
        for (int k = 0; k < 3; ++k) out[n * 288 + 32 + w * 3 + k] = o1[k] * inv;
    }
    // l=2 block (160 floats at offset 128), layout [w][k], k<5
    {
        float o2[5] = {0.f, 0.f, 0.f, 0.f, 0.f};
        #pragma unroll
        for (int u = 0; u < 8; ++u) {
            float c = 0.f;
            #pragma unroll
            for (int v = 0; v < 8; ++v) c += a[v] * W9[(u * 8 + v) * 32 + w];
            #pragma unroll
            for (int k = 0; k < 5; ++k) o2[k] += sM[ln][u * 9 + 4 + k] * c;
        }
        #pragma unroll
        for (int k = 0; k < 5; ++k) out[n * 288 + 128 + w * 5 + k] = o2[k] * inv;
    }
}

// ---------------- launch ---------------------------------------------------------
extern "C" void kernel_launch(void* const* d_in, const int* in_sizes, int n_in,
                              void* d_out, int out_size, void* d_ws, size_t ws_size,
                              hipStream_t stream) {
    const float* pos         = (const float*)d_in[0];
    const float* edge_shifts = (const float*)d_in[1];
    const float* cell        = (const float*)d_in[2];
    const float* atom_emb    = (const float*)d_in[3];
    const float* mlp_w1      = (const float*)d_in[4];
    const float* mlp_b1      = (const float*)d_in[5];
    const float* mlp_w2      = (const float*)d_in[6];
    const float* mlp_b2      = (const float*)d_in[7];
    const float* fc_w1       = (const float*)d_in[8];
    const float* fc_b1       = (const float*)d_in[9];
    const float* fc_w2       = (const float*)d_in[10];
    const float* fc_b2       = (const float*)d_in[11];
    const float* fc_w3       = (const float*)d_in[12];
    const float* fc_b3       = (const float*)d_in[13];
    const float* tp_w        = (const float*)d_in[14];
    const int*   A           = (const int*)d_in[15];
    const int*   batch       = (const int*)d_in[16];
    const int*   edge_src    = (const int*)d_in[17];
    const int*   edge_dst    = (const int*)d_in[18];
    float* out = (float*)d_out;

    // workspace layout (16B aligned):
    // floats: Ai[80000] | tab[(TN+1)*4] ; ints: deg[10000] | elist int2[10000*128]
    float*  Ai  = (float*)d_ws;
    float4* tab = (float4*)(Ai + N_NODES * 8);
    int*    deg   = (int*)(tab + (TN + 1));
    int2*   elist = (int2*)(deg + N_NODES);
    // total: ~11.2 MB

    hipMemsetAsync(deg, 0, N_NODES * sizeof(int), stream);

    bucket_kernel<<<N_EDGES / 256, 256, 0, stream>>>(edge_src, edge_dst, deg, elist);

    prep_kernel<<<AI_BLOCKS + TB_BLOCKS, 256, 0, stream>>>(
        atom_emb, A, mlp_w1, mlp_b1, mlp_w2, mlp_b2,
        fc_w1, fc_b1, fc_w2, fc_b2, fc_w3, fc_b3, Ai, tab);

    gather_out_kernel<<<N_NODES / 4, 256, 0, stream>>>(
        deg, elist, pos, edge_shifts, cell, batch, tab, Ai, tp_w, out);
}